// Round 7
// baseline (414.247 us; speedup 1.0000x reference)
//
#include <hip/hip_runtime.h>

#define BN_EPS 1e-5f

typedef short s8v __attribute__((ext_vector_type(8)));
typedef float f4v __attribute__((ext_vector_type(4)));
typedef unsigned short u4v __attribute__((ext_vector_type(4)));

__device__ __forceinline__ unsigned short f2bf(float f) {
  union { float f; unsigned u; } v; v.f = f;
  unsigned r = v.u + 0x7FFF + ((v.u >> 16) & 1);
  return (unsigned short)(r >> 16);
}
__device__ __forceinline__ float bf2f(unsigned short u) {
  union { unsigned u; float f; } v; v.u = ((unsigned)u) << 16; return v.f;
}

// ---------------------------------------------------------------- degree histogram (int)
__global__ __launch_bounds__(256) void deg_kernel(const int* __restrict__ dst,
                                                  int* __restrict__ deg, int E) {
  int e = blockIdx.x * 256 + threadIdx.x;
  if (e < E) atomicAdd(&deg[dst[e]], 1);
}

// ------------------------------------------- scan pass 1: per-block (1024 elems) totals
__global__ __launch_bounds__(256) void scan_partial_kernel(const int* __restrict__ deg,
    int* __restrict__ partials, int N) {
  __shared__ int sh[256];
  int t = threadIdx.x;
  int base = blockIdx.x * 1024 + t * 4;
  int s = 0;
#pragma unroll
  for (int i = 0; i < 4; ++i) {
    int idx = base + i;
    if (idx < N) s += deg[idx];
  }
  sh[t] = s;
  __syncthreads();
  for (int d = 128; d > 0; d >>= 1) {
    if (t < d) sh[t] += sh[t + d];
    __syncthreads();
  }
  if (t == 0) partials[blockIdx.x] = sh[0];
}

// ------------------------------------------- scan pass 2: exclusive scan of partials
__global__ __launch_bounds__(256) void scan_offsets_kernel(const int* __restrict__ partials,
    int* __restrict__ blk_off, int G) {
  __shared__ int sh[256];
  int t = threadIdx.x;
  sh[t] = (t < G) ? partials[t] : 0;
  __syncthreads();
  for (int d = 1; d < 256; d <<= 1) {
    int v = (t >= d) ? sh[t - d] : 0;
    __syncthreads();
    sh[t] += v;
    __syncthreads();
  }
  if (t < G) blk_off[t] = (t == 0) ? 0 : sh[t - 1];
}

// ----- scan pass 3: block-local exclusive scan + offset -> row_start, bucket cursors
__global__ __launch_bounds__(256) void scan_scatter_kernel(const int* __restrict__ deg,
    const int* __restrict__ blk_off, int* __restrict__ row_start,
    int* __restrict__ gcursor, int N) {
  __shared__ int sh[256];
  int t = threadIdx.x;
  int base = blockIdx.x * 1024 + t * 4;
  int v[4];
#pragma unroll
  for (int i = 0; i < 4; ++i) v[i] = (base + i < N) ? deg[base + i] : 0;
  sh[t] = v[0] + v[1] + v[2] + v[3];
  __syncthreads();
  for (int d = 1; d < 256; d <<= 1) {
    int u = (t >= d) ? sh[t - d] : 0;
    __syncthreads();
    sh[t] += u;
    __syncthreads();
  }
  int off = blk_off[blockIdx.x] + ((t == 0) ? 0 : sh[t - 1]);
#pragma unroll
  for (int i = 0; i < 4; ++i) {
    int idx = base + i;
    if (idx < N) {
      row_start[idx] = off;
      if ((idx & 127) == 0) gcursor[idx >> 7] = off;  // pairs cursor = CSR bucket start
      off += v[i];
    }
  }
}

// ------------------- CSR phase A: LDS-staged bucket scatter (kills partial-line writes)
#define CHUNK 8192
#define NBMAX 512
__global__ __launch_bounds__(256) void csr_bucket_kernel(
    const int* __restrict__ src, const int* __restrict__ dst,
    int* __restrict__ gcursor, unsigned* __restrict__ pairs, int E) {
  __shared__ int h[NBMAX];
  __shared__ int off[NBMAX];
  __shared__ int cnt2[NBMAX];
  __shared__ int gadj[NBMAX];
  __shared__ unsigned pbuf[CHUNK];
  __shared__ unsigned short bidx[CHUNK];
  int t = threadIdx.x;
  int base = blockIdx.x * CHUNK;
  int cnt = min(CHUNK, E - base);
  for (int i = t; i < NBMAX; i += 256) { h[i] = 0; cnt2[i] = 0; }
  __syncthreads();
  for (int i = t; i < cnt; i += 256) atomicAdd(&h[dst[base + i] >> 7], 1);
  __syncthreads();
  off[t] = h[t]; off[t + 256] = h[t + 256];
  __syncthreads();
  for (int d = 1; d < 512; d <<= 1) {
    int v0 = (t >= d) ? off[t - d] : 0;
    int v1 = off[t + 256 - d];
    __syncthreads();
    off[t] += v0; off[t + 256] += v1;
    __syncthreads();
  }
  int e0 = off[t] - h[t];
  int e1 = off[t + 256] - h[t + 256];
  __syncthreads();
  off[t] = e0; off[t + 256] = e1;
  __syncthreads();
  for (int i = t; i < NBMAX; i += 256) {
    int c = h[i];
    if (c > 0) gadj[i] = atomicAdd(&gcursor[i], c) - off[i];
  }
  __syncthreads();
  for (int i = t; i < cnt; i += 256) {
    int s = src[base + i];
    int d = dst[base + i];
    int b = d >> 7;
    int p = off[b] + atomicAdd(&cnt2[b], 1);
    pbuf[p] = (unsigned)s | ((unsigned)d << 16);   // both < 2^16 (N=50000)
    bidx[p] = (unsigned short)b;
  }
  __syncthreads();
  for (int i = t; i < cnt; i += 256)
    pairs[gadj[bidx[i]] + i] = pbuf[i];
}

// ------------------- CSR phase B: one block per bucket, private eidx region, LDS cursors
__global__ __launch_bounds__(256) void csr_fill_kernel(
    const unsigned* __restrict__ pairs, const int* __restrict__ row_start,
    int* __restrict__ eidx, int N, int E) {
  __shared__ int cur[128];
  int b = blockIdx.x;
  int node0 = b << 7;
  int t = threadIdx.x;
  if (t < 128) {
    int node = node0 + t;
    cur[t] = (node < N) ? row_start[node] : 0;
  }
  __syncthreads();
  int pbeg = row_start[node0];
  int pend = (node0 + 128 < N) ? row_start[node0 + 128] : E;
  for (int i = pbeg + t; i < pend; i += 256) {
    unsigned p = pairs[i];
    int pos = atomicAdd(&cur[(int)(p >> 16) - node0], 1);
    eidx[pos] = (int)(p & 0xFFFFu);
  }
}

// --------------- fused prep: xcast (blocks [0,xblocks)) + 6 weight transposes
__global__ __launch_bounds__(256) void prep_kernel(
    const float* __restrict__ x, unsigned short* __restrict__ xb,
    const float* __restrict__ Wl1, const float* __restrict__ Wr1,
    const float* __restrict__ Wl2, const float* __restrict__ Wr2,
    const float* __restrict__ W1, const float* __restrict__ W2,
    unsigned short* __restrict__ Wl1t, unsigned short* __restrict__ Wr1t,
    unsigned short* __restrict__ Wl2t, unsigned short* __restrict__ Wr2t,
    unsigned short* __restrict__ W1t, unsigned short* __restrict__ W2t,
    int N, int xblocks) {
  int blk = blockIdx.x;
  if (blk < xblocks) {
    int t = blk * 256 + threadIdx.x;
    if (t < N * 128) {
      int col = t & 127;
      int n = t >> 7;
      xb[t] = (col < 100) ? f2bf(x[n * 100 + col]) : (unsigned short)0;
    }
    return;
  }
  int w = blk - xblocks;
  const float* W; unsigned short* Wt; int K, C, base;
  if (w < 64)       { W = Wl1; Wt = Wl1t; K = 100; C = 128; base = 0;   }
  else if (w < 128) { W = Wr1; Wt = Wr1t; K = 100; C = 128; base = 64;  }
  else if (w < 192) { W = Wl2; Wt = Wl2t; K = 128; C = 128; base = 128; }
  else if (w < 256) { W = Wr2; Wt = Wr2t; K = 128; C = 128; base = 192; }
  else if (w < 320) { W = W1;  Wt = W1t;  K = 128; C = 128; base = 256; }
  else              { W = W2;  Wt = W2t;  K = 128; C = 64;  base = 320; }
  int t = (w - base) * 256 + threadIdx.x;
  if (t >= C * 128) return;
  int c = t >> 7;
  int k = t & 127;
  Wt[t] = (k < K) ? f2bf(W[k * C + c]) : (unsigned short)0;
}

// ---------------- fused gather-mean + SAGE MFMA: relu(mean@Wl + bl + self@Wr)
// 64 rows/block. Means gathered into LDS (stride 136 -> aligned b128, conflict-free),
// epilogue fp32 tile aliases the mean buffer (sync in between). R6: the bare GEMM was
// latency-bound (MfmaUtil 2.5%, all idle) -- the gather's ~1K independent row-reads
// per block now fill those bubbles and the mean round-trip through HBM/LLC is gone.
__global__ __launch_bounds__(256) void sage_fused_kernel(
    const unsigned short* __restrict__ feat,   // [N][128] gather source + self features
    const int* __restrict__ eidx, const int* __restrict__ row_start,
    const int* __restrict__ deg,
    const unsigned short* __restrict__ Wlt, const unsigned short* __restrict__ Wrt,
    const float* __restrict__ bl,
    float* __restrict__ outF, unsigned short* __restrict__ outB, int N) {
  const int RS = 136;                         // padded row stride (16B-aligned rows)
  __shared__ char smem[64 * RS * 4];          // 34816 B, dual-use
  __shared__ int sdeg[64];
  __shared__ int srow[64];
  unsigned short* meanb = (unsigned short*)smem;
  float* lds = (float*)smem;

  int t = threadIdx.x;
  int wave = t >> 6, lane = t & 63;
  int quad = lane >> 4, m = lane & 15;
  int nblk = blockIdx.x * 64;

  if (t < 64) {
    int node = nblk + t;
    sdeg[t] = (node < N) ? deg[node] : 0;
    srow[t] = (node < N) ? row_start[node] : 0;
  }
  __syncthreads();

  // ---- gather phase: wave w produces mean rows [w*16, w*16+16)
  for (int nn = 0; nn < 16; ++nn) {
    int ln = wave * 16 + nn;
    int d = sdeg[ln];
    int beg = srow[ln];
    float a0 = 0.0f, a1 = 0.0f;
    for (int i0 = 0; i0 < d; i0 += 64) {
      int cnt = min(64, d - i0);
      int my = (lane < cnt) ? eidx[beg + i0 + lane] : 0;
      int j = 0;
      for (; j + 3 < cnt; j += 4) {
        int s0 = __shfl(my, j + 0);
        int s1 = __shfl(my, j + 1);
        int s2 = __shfl(my, j + 2);
        int s3 = __shfl(my, j + 3);
        unsigned v0 = ((const unsigned*)(feat + (size_t)s0 * 128))[lane];
        unsigned v1 = ((const unsigned*)(feat + (size_t)s1 * 128))[lane];
        unsigned v2 = ((const unsigned*)(feat + (size_t)s2 * 128))[lane];
        unsigned v3 = ((const unsigned*)(feat + (size_t)s3 * 128))[lane];
        a0 += bf2f((unsigned short)v0) + bf2f((unsigned short)v1)
            + bf2f((unsigned short)v2) + bf2f((unsigned short)v3);
        a1 += bf2f((unsigned short)(v0 >> 16)) + bf2f((unsigned short)(v1 >> 16))
            + bf2f((unsigned short)(v2 >> 16)) + bf2f((unsigned short)(v3 >> 16));
      }
      for (; j < cnt; ++j) {
        int s0 = __shfl(my, j);
        unsigned v0 = ((const unsigned*)(feat + (size_t)s0 * 128))[lane];
        a0 += bf2f((unsigned short)v0);
        a1 += bf2f((unsigned short)(v0 >> 16));
      }
    }
    float inv = 1.0f / fmaxf((float)d, 1.0f);
    unsigned o = (unsigned)f2bf(a0 * inv) | ((unsigned)f2bf(a1 * inv) << 16);
    ((unsigned*)(meanb + ln * RS))[lane] = o;
  }
  __syncthreads();

  // ---- preload A fragments (mean from LDS, self from global, clamped row)
  int arow = wave * 16 + m;
  int grow = nblk + arow;
  int crow = (grow < N) ? grow : (N - 1);
  s8v a1f[4], a2f[4];
  const unsigned short* mrow = meanb + arow * RS + quad * 8;
  const unsigned short* frow = feat + (size_t)crow * 128 + quad * 8;
#pragma unroll
  for (int kk = 0; kk < 4; ++kk) {
    a1f[kk] = *(const s8v*)(mrow + kk * 32);
    a2f[kk] = *(const s8v*)(frow + kk * 32);
  }
  __syncthreads();   // meanb dead; fp32 epilogue may now alias it

  // ---- MFMA
  f4v acc[8];
#pragma unroll
  for (int ct = 0; ct < 8; ++ct) acc[ct] = (f4v){0.f, 0.f, 0.f, 0.f};
#pragma unroll
  for (int kk = 0; kk < 4; ++kk) {
    int k0 = kk * 32;
#pragma unroll
    for (int ct = 0; ct < 8; ++ct) {
      s8v b1 = *(const s8v*)(Wlt + (size_t)(ct * 16 + m) * 128 + k0 + quad * 8);
      acc[ct] = __builtin_amdgcn_mfma_f32_16x16x32_bf16(a1f[kk], b1, acc[ct], 0, 0, 0);
      s8v b2 = *(const s8v*)(Wrt + (size_t)(ct * 16 + m) * 128 + k0 + quad * 8);
      acc[ct] = __builtin_amdgcn_mfma_f32_16x16x32_bf16(a2f[kk], b2, acc[ct], 0, 0, 0);
    }
  }
  // ---- epilogue: bias + relu -> LDS (D layout col=lane&15, row=quad*4+reg)
#pragma unroll
  for (int ct = 0; ct < 8; ++ct) {
    int col = ct * 16 + m;
    float b = bl[col];
#pragma unroll
    for (int r = 0; r < 4; ++r) {
      float v = fmaxf(acc[ct][r] + b, 0.0f);
      lds[(wave * 16 + quad * 4 + r) * RS + col] = v;
    }
  }
  __syncthreads();
  for (int idx = t; idx < 64 * 128; idx += 256) {
    int row = idx >> 7;
    int col = idx & 127;
    int gr = nblk + row;
    if (gr < N) {
      float v = lds[row * RS + col];
      outF[(size_t)gr * 128 + col] = v;
      outB[(size_t)gr * 128 + col] = f2bf(v);
    }
  }
}

// --------------------------------------------------------- MFMA GEMM (K padded to 128)
// STATS: block LDS reduction -> 1 atomic/col/block into 8-way-spread slots.
template<int COLS, bool F32OUT, bool BF16OUT, bool STATS>
__global__ __launch_bounds__(256) void mfma_gemm_kernel(
    const unsigned short* __restrict__ A1, const unsigned short* __restrict__ W1t,
    const float* __restrict__ bias,
    float* __restrict__ outF, unsigned short* __restrict__ outB,
    float* __restrict__ sum, float* __restrict__ sq, int N) {
  const int CT = COLS / 16;
  __shared__ float lds[64][COLS + 4];
  __shared__ float red[STATS ? 512 : 1];
  int wave = threadIdx.x >> 6;
  int lane = threadIdx.x & 63;
  int quad = lane >> 4;
  int m = lane & 15;
  int n0 = blockIdx.x * 64 + wave * 16;
  bool valid = (n0 < N);

  f4v acc[CT];
#pragma unroll
  for (int ct = 0; ct < CT; ++ct) acc[ct] = (f4v){0.f, 0.f, 0.f, 0.f};

  if (valid) {
    const unsigned short* a1p = A1 + (size_t)(n0 + m) * 128 + quad * 8;
#pragma unroll
    for (int k0 = 0; k0 < 128; k0 += 32) {
      s8v a1 = *(const s8v*)(a1p + k0);
#pragma unroll
      for (int ct = 0; ct < CT; ++ct) {
        s8v b1 = *(const s8v*)(W1t + (size_t)(ct * 16 + m) * 128 + k0 + quad * 8);
        acc[ct] = __builtin_amdgcn_mfma_f32_16x16x32_bf16(a1, b1, acc[ct], 0, 0, 0);
      }
    }
#pragma unroll
    for (int ct = 0; ct < CT; ++ct) {
      int col = ct * 16 + m;
      float b = bias[col];
#pragma unroll
      for (int r = 0; r < 4; ++r)
        lds[wave * 16 + quad * 4 + r][col] = acc[ct][r] + b;
    }
  }
  __syncthreads();
  int blk = blockIdx.x * 64;
  float s = 0.0f, ss = 0.0f;
  for (int idx = threadIdx.x; idx < 64 * COLS; idx += 256) {
    int row = idx / COLS;
    int col = idx % COLS;   // constant per thread (256 % COLS == 0)
    int gr = blk + row;
    if (gr < N) {
      float v = lds[row][col];
      if (F32OUT) outF[(size_t)gr * COLS + col] = v;
      if (BF16OUT) outB[(size_t)gr * COLS + col] = f2bf(v);
      if (STATS) { s += v; ss += v * v; }
    }
  }
  if (STATS) {
    int t = threadIdx.x;
    red[t] = s;
    red[256 + t] = ss;
    __syncthreads();
    if (t < COLS) {
      float S = 0.0f, SS = 0.0f;
#pragma unroll
      for (int g = 0; g < 256 / COLS; ++g) {
        S  += red[t + g * COLS];
        SS += red[256 + t + g * COLS];
      }
      int slot = (blockIdx.x & 7) * COLS + t;
      atomicAdd(&sum[slot], S);
      atomicAdd(&sq[slot], SS);
    }
  }
}

// --------- BN (train) + ReLU: bf16 in -> bf16 out (C = 128, 8 stat slots), 4 elems/thr
__global__ __launch_bounds__(256) void bn_relu_kernel(const unsigned short* __restrict__ y,
    int N, const float* __restrict__ sum, const float* __restrict__ sumsq,
    const float* __restrict__ g, const float* __restrict__ be,
    unsigned short* __restrict__ yb) {
  int t4 = blockIdx.x * 256 + threadIdx.x;
  if (t4 >= N * 32) return;
  int col0 = (t4 & 31) * 4;
  float invN = 1.0f / (float)N;
  u4v in = *(const u4v*)(y + (size_t)t4 * 4);
  u4v outv;
#pragma unroll
  for (int i = 0; i < 4; ++i) {
    int col = col0 + i;
    float S = 0.0f, SS = 0.0f;
#pragma unroll
    for (int k = 0; k < 8; ++k) { S += sum[k * 128 + col]; SS += sumsq[k * 128 + col]; }
    float m = S * invN;
    float v = SS * invN - m * m;
    float val = (bf2f(in[i]) - m) * rsqrtf(v + BN_EPS) * g[col] + be[col];
    outv[i] = f2bf(fmaxf(val, 0.0f));
  }
  *(u4v*)(yb + (size_t)t4 * 4) = outv;
}

// ---------- fused BN(train)+ReLU (64 cols, 8 stat slots) + head dot: out = z2@W3+b3
__global__ __launch_bounds__(256) void bn_head_kernel(const float* __restrict__ y2,
    const float* __restrict__ sum, const float* __restrict__ sumsq,
    const float* __restrict__ g, const float* __restrict__ be,
    const float* __restrict__ W3, const float* __restrict__ b3,
    float* __restrict__ out, int N) {
  int wave = threadIdx.x >> 6;
  int lane = threadIdx.x & 63;
  int row = blockIdx.x * 4 + wave;
  if (row >= N) return;
  float S = 0.0f, SS = 0.0f;
#pragma unroll
  for (int k = 0; k < 8; ++k) { S += sum[k * 64 + lane]; SS += sumsq[k * 64 + lane]; }
  float invN = 1.0f / (float)N;
  float m = S * invN;
  float var = SS * invN - m * m;
  float val = (y2[(size_t)row * 64 + lane] - m) * rsqrtf(var + BN_EPS) * g[lane] + be[lane];
  val = fmaxf(val, 0.0f) * W3[lane];
#pragma unroll
  for (int off = 32; off > 0; off >>= 1) val += __shfl_down(val, off);
  if (lane == 0) out[row] = val + b3[0];
}

// ================================================================ launch
extern "C" void kernel_launch(void* const* d_in, const int* in_sizes, int n_in,
                              void* d_out, int out_size, void* d_ws, size_t ws_size,
                              hipStream_t stream) {
  const int F = 100, H = 128;
  const int N = in_sizes[0] / F;
  const int E = in_sizes[1] / 2;

  const float* x   = (const float*)d_in[0];
  const int* edge  = (const int*)d_in[1];
  const int* src   = edge;
  const int* dst   = edge + E;
  const float* Wl1 = (const float*)d_in[2];
  const float* bl1 = (const float*)d_in[3];
  const float* Wr1 = (const float*)d_in[4];
  const float* Wl2 = (const float*)d_in[5];
  const float* bl2 = (const float*)d_in[6];
  const float* Wr2 = (const float*)d_in[7];
  const float* W1  = (const float*)d_in[8];
  const float* b1  = (const float*)d_in[9];
  const float* g1  = (const float*)d_in[10];
  const float* be1 = (const float*)d_in[11];
  const float* W2  = (const float*)d_in[12];
  const float* b2  = (const float*)d_in[13];
  const float* g2  = (const float*)d_in[14];
  const float* be2 = (const float*)d_in[15];
  const float* W3  = (const float*)d_in[16];
  const float* b3  = (const float*)d_in[17];

  float* out0 = (float*)d_out;              // [N]
  float* h1   = out0 + N;                   // [N,128] fp32 (required output)
  float* h2   = h1 + (size_t)N * H;         // [N,128] fp32 (required output)

  const int SCAN_G = (N + 1023) / 1024;     // 49
  const int NB = (N + 127) / 128;           // 391 buckets

  // ---- workspace layout
  char* wsp = (char*)d_ws;
  int* deg       = (int*)wsp;               wsp += (size_t)N * sizeof(int);
  int* row_start = (int*)wsp;               wsp += (size_t)N * sizeof(int);
  int* eidx      = (int*)wsp;               wsp += (size_t)E * sizeof(int);
  unsigned* pairs = (unsigned*)wsp;         wsp += (size_t)E * sizeof(unsigned);
  int* gcursor   = (int*)wsp;               wsp += 512 * sizeof(int);
  int* partials  = (int*)wsp;               wsp += 256 * sizeof(int);
  int* blk_off   = (int*)wsp;               wsp += 256 * sizeof(int);
  float* sum1    = (float*)wsp;             wsp += 8 * 128 * sizeof(float);
  float* sq1     = (float*)wsp;             wsp += 8 * 128 * sizeof(float);
  float* sum2    = (float*)wsp;             wsp += 8 * 64 * sizeof(float);
  float* sq2     = (float*)wsp;             wsp += 8 * 64 * sizeof(float);
  float* bufA    = (float*)wsp;             wsp += (size_t)N * 128 * sizeof(float);
  unsigned short* bfX = (unsigned short*)wsp; wsp += (size_t)N * 128 * 2; // xb -> z1b
  unsigned short* bfM = (unsigned short*)wsp; wsp += (size_t)N * 128 * 2; // h2b
  unsigned short* bfH = (unsigned short*)wsp; wsp += (size_t)N * 128 * 2; // h1b
  unsigned short* Wl1t = (unsigned short*)wsp; wsp += 128 * 128 * 2;
  unsigned short* Wr1t = (unsigned short*)wsp; wsp += 128 * 128 * 2;
  unsigned short* Wl2t = (unsigned short*)wsp; wsp += 128 * 128 * 2;
  unsigned short* Wr2t = (unsigned short*)wsp; wsp += 128 * 128 * 2;
  unsigned short* W1t  = (unsigned short*)wsp; wsp += 128 * 128 * 2;
  unsigned short* W2t  = (unsigned short*)wsp; wsp += 64 * 128 * 2;

  unsigned short* y1b = (unsigned short*)bufA;                    // [N,128] bf16
  float* y2 = (float*)((char*)bufA + (size_t)N * 128 * 2);        // [N,64] fp32

  // ---- zero-init accumulated scratch (ws poisoned 0xAA each call)
  hipMemsetAsync(deg, 0, (size_t)N * sizeof(int), stream);
  hipMemsetAsync(sum1, 0, (8 * 128 + 8 * 128 + 8 * 64 + 8 * 64) * sizeof(float), stream);

  // ---- build CSR (dst -> list of src)
  deg_kernel<<<(E + 255) / 256, 256, 0, stream>>>(dst, deg, E);
  scan_partial_kernel<<<SCAN_G, 256, 0, stream>>>(deg, partials, N);
  scan_offsets_kernel<<<1, 256, 0, stream>>>(partials, blk_off, SCAN_G);
  scan_scatter_kernel<<<SCAN_G, 256, 0, stream>>>(deg, blk_off, row_start, gcursor, N);
  csr_bucket_kernel<<<(E + CHUNK - 1) / CHUNK, 256, 0, stream>>>(src, dst, gcursor, pairs, E);
  csr_fill_kernel<<<NB, 256, 0, stream>>>(pairs, row_start, eidx, N, E);

  // ---- fused bf16 prep (xcast + all weight transposes)
  int xblocks = ((size_t)N * 128 + 255) / 256;
  prep_kernel<<<xblocks + 352, 256, 0, stream>>>(x, bfX,
      Wl1, Wr1, Wl2, Wr2, W1, W2, Wl1t, Wr1t, Wl2t, Wr2t, W1t, W2t, N, xblocks);

  int gemm_grid = (N + 63) / 64;

  // ---- layer 1: fused gather+SAGE on xb -> h1 (fp32) + h1b (bfH)
  sage_fused_kernel<<<gemm_grid, 256, 0, stream>>>(
      bfX, eidx, row_start, deg, Wl1t, Wr1t, bl1, h1, bfH, N);

  // ---- layer 2: fused gather+SAGE on h1b -> h2 (fp32) + h2b (bfM)
  sage_fused_kernel<<<gemm_grid, 256, 0, stream>>>(
      bfH, eidx, row_start, deg, Wl2t, Wr2t, bl2, h2, bfM, N);

  // ---- MLP layer 1: y1 = h2b @ W1 + b1 -> y1b (bf16) + fused col stats
  mfma_gemm_kernel<128, false, true, true><<<gemm_grid, 256, 0, stream>>>(
      bfM, W1t, b1, nullptr, y1b, sum1, sq1, N);
  bn_relu_kernel<<<((size_t)N * 32 + 255) / 256, 256, 0, stream>>>(
      y1b, N, sum1, sq1, g1, be1, bfX);

  // ---- MLP layer 2: y2 = z1b @ W2 + b2 (fp32) + fused col stats
  mfma_gemm_kernel<64, true, false, true><<<gemm_grid, 256, 0, stream>>>(
      bfX, W2t, b2, y2, nullptr, sum2, sq2, N);

  // ---- fused BN+ReLU+head: out = relu(bn(y2)) @ W3 + b3
  bn_head_kernel<<<(N + 3) / 4, 256, 0, stream>>>(
      y2, sum2, sq2, g2, be2, W3, b3, out0, N);
}

// Round 8
// 389.674 us; speedup vs baseline: 1.0631x; 1.0631x over previous
//
#include <hip/hip_runtime.h>

#define BN_EPS 1e-5f

typedef short s8v __attribute__((ext_vector_type(8)));
typedef float f4v __attribute__((ext_vector_type(4)));
typedef unsigned short u4v __attribute__((ext_vector_type(4)));

__device__ __forceinline__ unsigned short f2bf(float f) {
  union { float f; unsigned u; } v; v.f = f;
  unsigned r = v.u + 0x7FFF + ((v.u >> 16) & 1);
  return (unsigned short)(r >> 16);
}
__device__ __forceinline__ float bf2f(unsigned short u) {
  union { unsigned u; float f; } v; v.u = ((unsigned)u) << 16; return v.f;
}

// ---------------------------------------------------------------- degree histogram (int)
__global__ __launch_bounds__(256) void deg_kernel(const int* __restrict__ dst,
                                                  int* __restrict__ deg, int E) {
  int e = blockIdx.x * 256 + threadIdx.x;
  if (e < E) atomicAdd(&deg[dst[e]], 1);
}

// ------------------------------------------- scan pass 1: per-block (1024 elems) totals
__global__ __launch_bounds__(256) void scan_partial_kernel(const int* __restrict__ deg,
    int* __restrict__ partials, int N) {
  __shared__ int sh[256];
  int t = threadIdx.x;
  int base = blockIdx.x * 1024 + t * 4;
  int s = 0;
#pragma unroll
  for (int i = 0; i < 4; ++i) {
    int idx = base + i;
    if (idx < N) s += deg[idx];
  }
  sh[t] = s;
  __syncthreads();
  for (int d = 128; d > 0; d >>= 1) {
    if (t < d) sh[t] += sh[t + d];
    __syncthreads();
  }
  if (t == 0) partials[blockIdx.x] = sh[0];
}

// ------------------------------------------- scan pass 2: exclusive scan of partials
__global__ __launch_bounds__(256) void scan_offsets_kernel(const int* __restrict__ partials,
    int* __restrict__ blk_off, int G) {
  __shared__ int sh[256];
  int t = threadIdx.x;
  sh[t] = (t < G) ? partials[t] : 0;
  __syncthreads();
  for (int d = 1; d < 256; d <<= 1) {
    int v = (t >= d) ? sh[t - d] : 0;
    __syncthreads();
    sh[t] += v;
    __syncthreads();
  }
  if (t < G) blk_off[t] = (t == 0) ? 0 : sh[t - 1];
}

// ----- scan pass 3: block-local exclusive scan + offset -> row_start, bucket cursors
__global__ __launch_bounds__(256) void scan_scatter_kernel(const int* __restrict__ deg,
    const int* __restrict__ blk_off, int* __restrict__ row_start,
    int* __restrict__ gcursor, int N) {
  __shared__ int sh[256];
  int t = threadIdx.x;
  int base = blockIdx.x * 1024 + t * 4;
  int v[4];
#pragma unroll
  for (int i = 0; i < 4; ++i) v[i] = (base + i < N) ? deg[base + i] : 0;
  sh[t] = v[0] + v[1] + v[2] + v[3];
  __syncthreads();
  for (int d = 1; d < 256; d <<= 1) {
    int u = (t >= d) ? sh[t - d] : 0;
    __syncthreads();
    sh[t] += u;
    __syncthreads();
  }
  int off = blk_off[blockIdx.x] + ((t == 0) ? 0 : sh[t - 1]);
#pragma unroll
  for (int i = 0; i < 4; ++i) {
    int idx = base + i;
    if (idx < N) {
      row_start[idx] = off;
      if ((idx & 127) == 0) gcursor[idx >> 7] = off;  // pairs cursor = CSR bucket start
      off += v[i];
    }
  }
}

// ------------------- CSR phase A: LDS-staged bucket scatter (kills partial-line writes)
#define CHUNK 8192
#define NBMAX 512
__global__ __launch_bounds__(256) void csr_bucket_kernel(
    const int* __restrict__ src, const int* __restrict__ dst,
    int* __restrict__ gcursor, unsigned* __restrict__ pairs, int E) {
  __shared__ int h[NBMAX];
  __shared__ int off[NBMAX];
  __shared__ int cnt2[NBMAX];
  __shared__ int gadj[NBMAX];
  __shared__ unsigned pbuf[CHUNK];
  __shared__ unsigned short bidx[CHUNK];
  int t = threadIdx.x;
  int base = blockIdx.x * CHUNK;
  int cnt = min(CHUNK, E - base);
  for (int i = t; i < NBMAX; i += 256) { h[i] = 0; cnt2[i] = 0; }
  __syncthreads();
  for (int i = t; i < cnt; i += 256) atomicAdd(&h[dst[base + i] >> 7], 1);
  __syncthreads();
  off[t] = h[t]; off[t + 256] = h[t + 256];
  __syncthreads();
  for (int d = 1; d < 512; d <<= 1) {
    int v0 = (t >= d) ? off[t - d] : 0;
    int v1 = off[t + 256 - d];
    __syncthreads();
    off[t] += v0; off[t + 256] += v1;
    __syncthreads();
  }
  int e0 = off[t] - h[t];
  int e1 = off[t + 256] - h[t + 256];
  __syncthreads();
  off[t] = e0; off[t + 256] = e1;
  __syncthreads();
  for (int i = t; i < NBMAX; i += 256) {
    int c = h[i];
    if (c > 0) gadj[i] = atomicAdd(&gcursor[i], c) - off[i];
  }
  __syncthreads();
  for (int i = t; i < cnt; i += 256) {
    int s = src[base + i];
    int d = dst[base + i];
    int b = d >> 7;
    int p = off[b] + atomicAdd(&cnt2[b], 1);
    pbuf[p] = (unsigned)s | ((unsigned)d << 16);   // both < 2^16 (N=50000)
    bidx[p] = (unsigned short)b;
  }
  __syncthreads();
  for (int i = t; i < cnt; i += 256)
    pairs[gadj[bidx[i]] + i] = pbuf[i];
}

// ------------------- CSR phase B: one block per bucket, private eidx region, LDS cursors
__global__ __launch_bounds__(256) void csr_fill_kernel(
    const unsigned* __restrict__ pairs, const int* __restrict__ row_start,
    int* __restrict__ eidx, int N, int E) {
  __shared__ int cur[128];
  int b = blockIdx.x;
  int node0 = b << 7;
  int t = threadIdx.x;
  if (t < 128) {
    int node = node0 + t;
    cur[t] = (node < N) ? row_start[node] : 0;
  }
  __syncthreads();
  int pbeg = row_start[node0];
  int pend = (node0 + 128 < N) ? row_start[node0 + 128] : E;
  for (int i = pbeg + t; i < pend; i += 256) {
    unsigned p = pairs[i];
    int pos = atomicAdd(&cur[(int)(p >> 16) - node0], 1);
    eidx[pos] = (int)(p & 0xFFFFu);
  }
}

// --------------- fused prep: xcast (blocks [0,xblocks)) + 6 weight transposes
__global__ __launch_bounds__(256) void prep_kernel(
    const float* __restrict__ x, unsigned short* __restrict__ xb,
    const float* __restrict__ Wl1, const float* __restrict__ Wr1,
    const float* __restrict__ Wl2, const float* __restrict__ Wr2,
    const float* __restrict__ W1, const float* __restrict__ W2,
    unsigned short* __restrict__ Wl1t, unsigned short* __restrict__ Wr1t,
    unsigned short* __restrict__ Wl2t, unsigned short* __restrict__ Wr2t,
    unsigned short* __restrict__ W1t, unsigned short* __restrict__ W2t,
    int N, int xblocks) {
  int blk = blockIdx.x;
  if (blk < xblocks) {
    int t = blk * 256 + threadIdx.x;
    if (t < N * 128) {
      int col = t & 127;
      int n = t >> 7;
      xb[t] = (col < 100) ? f2bf(x[n * 100 + col]) : (unsigned short)0;
    }
    return;
  }
  int w = blk - xblocks;
  const float* W; unsigned short* Wt; int K, C, base;
  if (w < 64)       { W = Wl1; Wt = Wl1t; K = 100; C = 128; base = 0;   }
  else if (w < 128) { W = Wr1; Wt = Wr1t; K = 100; C = 128; base = 64;  }
  else if (w < 192) { W = Wl2; Wt = Wl2t; K = 128; C = 128; base = 128; }
  else if (w < 256) { W = Wr2; Wt = Wr2t; K = 128; C = 128; base = 192; }
  else if (w < 320) { W = W1;  Wt = W1t;  K = 128; C = 128; base = 256; }
  else              { W = W2;  Wt = W2t;  K = 128; C = 64;  base = 320; }
  int t = (w - base) * 256 + threadIdx.x;
  if (t >= C * 128) return;
  int c = t >> 7;
  int k = t & 127;
  Wt[t] = (k < K) ? f2bf(W[k * C + c]) : (unsigned short)0;
}

// ------------------------------------------ gather mean over bf16 rows (1 wave / node)
// R7 lesson: keep this standalone (50000 waves of TLP). Unroll-8 -> 8 independent
// 256B row reads in flight per wave (latency-bound path, Little's law).
__global__ __launch_bounds__(256) void gather_kernel(
    const unsigned short* __restrict__ feat, const int* __restrict__ eidx,
    const int* __restrict__ row_start, const int* __restrict__ deg,
    unsigned short* __restrict__ mean_out, int N) {
  int wave = threadIdx.x >> 6;
  int lane = threadIdx.x & 63;
  int node = blockIdx.x * 4 + wave;
  if (node >= N) return;
  int beg = row_start[node];
  int d = deg[node];
  float a0 = 0.0f, a1 = 0.0f;
  for (int i0 = 0; i0 < d; i0 += 64) {
    int cnt = min(64, d - i0);
    int my = (lane < cnt) ? eidx[beg + i0 + lane] : 0;
    int j = 0;
    for (; j + 7 < cnt; j += 8) {
      int s0 = __shfl(my, j + 0);
      int s1 = __shfl(my, j + 1);
      int s2 = __shfl(my, j + 2);
      int s3 = __shfl(my, j + 3);
      int s4 = __shfl(my, j + 4);
      int s5 = __shfl(my, j + 5);
      int s6 = __shfl(my, j + 6);
      int s7 = __shfl(my, j + 7);
      unsigned v0 = ((const unsigned*)(feat + (size_t)s0 * 128))[lane];
      unsigned v1 = ((const unsigned*)(feat + (size_t)s1 * 128))[lane];
      unsigned v2 = ((const unsigned*)(feat + (size_t)s2 * 128))[lane];
      unsigned v3 = ((const unsigned*)(feat + (size_t)s3 * 128))[lane];
      unsigned v4 = ((const unsigned*)(feat + (size_t)s4 * 128))[lane];
      unsigned v5 = ((const unsigned*)(feat + (size_t)s5 * 128))[lane];
      unsigned v6 = ((const unsigned*)(feat + (size_t)s6 * 128))[lane];
      unsigned v7 = ((const unsigned*)(feat + (size_t)s7 * 128))[lane];
      a0 += bf2f((unsigned short)v0) + bf2f((unsigned short)v1)
          + bf2f((unsigned short)v2) + bf2f((unsigned short)v3)
          + bf2f((unsigned short)v4) + bf2f((unsigned short)v5)
          + bf2f((unsigned short)v6) + bf2f((unsigned short)v7);
      a1 += bf2f((unsigned short)(v0 >> 16)) + bf2f((unsigned short)(v1 >> 16))
          + bf2f((unsigned short)(v2 >> 16)) + bf2f((unsigned short)(v3 >> 16))
          + bf2f((unsigned short)(v4 >> 16)) + bf2f((unsigned short)(v5 >> 16))
          + bf2f((unsigned short)(v6 >> 16)) + bf2f((unsigned short)(v7 >> 16));
    }
    for (; j < cnt; ++j) {
      int s0 = __shfl(my, j);
      unsigned v0 = ((const unsigned*)(feat + (size_t)s0 * 128))[lane];
      a0 += bf2f((unsigned short)v0);
      a1 += bf2f((unsigned short)(v0 >> 16));
    }
  }
  float inv = 1.0f / fmaxf((float)d, 1.0f);
  unsigned o = (unsigned)f2bf(a0 * inv) | ((unsigned)f2bf(a1 * inv) << 16);
  ((unsigned*)(mean_out + (size_t)node * 128))[lane] = o;
}

// --------------------------------------------------------- MFMA GEMM (K padded to 128)
// STATS: block LDS reduction -> 1 atomic/col/block into 8-way-spread slots (R5 lesson).
template<int COLS, bool DUAL, bool RELU, bool F32OUT, bool BF16OUT, bool STATS>
__global__ __launch_bounds__(256) void mfma_gemm_kernel(
    const unsigned short* __restrict__ A1, const unsigned short* __restrict__ W1t,
    const unsigned short* __restrict__ A2, const unsigned short* __restrict__ W2t,
    const float* __restrict__ bias,
    float* __restrict__ outF, unsigned short* __restrict__ outB,
    float* __restrict__ sum, float* __restrict__ sq, int N) {
  const int CT = COLS / 16;
  __shared__ float lds[64][COLS + 4];
  __shared__ float red[STATS ? 512 : 1];
  int wave = threadIdx.x >> 6;
  int lane = threadIdx.x & 63;
  int quad = lane >> 4;
  int m = lane & 15;
  int n0 = blockIdx.x * 64 + wave * 16;
  bool valid = (n0 < N);

  f4v acc[CT];
#pragma unroll
  for (int ct = 0; ct < CT; ++ct) acc[ct] = (f4v){0.f, 0.f, 0.f, 0.f};

  if (valid) {
    const unsigned short* a1p = A1 + (size_t)(n0 + m) * 128 + quad * 8;
    const unsigned short* a2p = DUAL ? (A2 + (size_t)(n0 + m) * 128 + quad * 8) : nullptr;
#pragma unroll
    for (int k0 = 0; k0 < 128; k0 += 32) {
      s8v a1 = *(const s8v*)(a1p + k0);
      s8v a2;
      if (DUAL) a2 = *(const s8v*)(a2p + k0);
#pragma unroll
      for (int ct = 0; ct < CT; ++ct) {
        s8v b1 = *(const s8v*)(W1t + (size_t)(ct * 16 + m) * 128 + k0 + quad * 8);
        acc[ct] = __builtin_amdgcn_mfma_f32_16x16x32_bf16(a1, b1, acc[ct], 0, 0, 0);
        if (DUAL) {
          s8v b2 = *(const s8v*)(W2t + (size_t)(ct * 16 + m) * 128 + k0 + quad * 8);
          acc[ct] = __builtin_amdgcn_mfma_f32_16x16x32_bf16(a2, b2, acc[ct], 0, 0, 0);
        }
      }
    }
#pragma unroll
    for (int ct = 0; ct < CT; ++ct) {
      int col = ct * 16 + m;
      float b = bias[col];
#pragma unroll
      for (int r = 0; r < 4; ++r) {
        float v = acc[ct][r] + b;
        if (RELU) v = fmaxf(v, 0.0f);
        lds[wave * 16 + quad * 4 + r][col] = v;
      }
    }
  }
  __syncthreads();
  int blk = blockIdx.x * 64;
  float s = 0.0f, ss = 0.0f;
  for (int idx = threadIdx.x; idx < 64 * COLS; idx += 256) {
    int row = idx / COLS;
    int col = idx % COLS;   // constant per thread (256 % COLS == 0)
    int gr = blk + row;
    if (gr < N) {
      float v = lds[row][col];
      if (F32OUT) outF[(size_t)gr * COLS + col] = v;
      if (BF16OUT) outB[(size_t)gr * COLS + col] = f2bf(v);
      if (STATS) { s += v; ss += v * v; }
    }
  }
  if (STATS) {
    int t = threadIdx.x;
    red[t] = s;
    red[256 + t] = ss;
    __syncthreads();
    if (t < COLS) {
      float S = 0.0f, SS = 0.0f;
#pragma unroll
      for (int g = 0; g < 256 / COLS; ++g) {
        S  += red[t + g * COLS];
        SS += red[256 + t + g * COLS];
      }
      int slot = (blockIdx.x & 7) * COLS + t;
      atomicAdd(&sum[slot], S);
      atomicAdd(&sq[slot], SS);
    }
  }
}

// ------------- fused sage2 + MLP1: h2 = relu(mean@Wl2 + h1b@Wr2 + bl2) -> h2 fp32;
//               y1 = h2(bf16)@W1 + b1 -> y1b bf16 + 8-slot col stats.
// The h2 tile sits in LDS for the coalesced store anyway; re-reading it as phase-2
// A-fragments deletes the standalone MLP1 kernel and the h2b global round-trip.
__global__ __launch_bounds__(256) void sage_mlp_kernel(
    const unsigned short* __restrict__ A1,   // mean2b
    const unsigned short* __restrict__ Wlt,
    const unsigned short* __restrict__ A2,   // h1b (self)
    const unsigned short* __restrict__ Wrt,
    const float* __restrict__ bl,
    const unsigned short* __restrict__ W1t, const float* __restrict__ b1,
    float* __restrict__ h2out, unsigned short* __restrict__ y1b,
    float* __restrict__ sum, float* __restrict__ sq, int N) {
  const int RS = 132;                      // fp32 row stride (132%4==0 -> b128-aligned)
  __shared__ float lds[64 * RS];
  __shared__ float red[512];
  int t = threadIdx.x;
  int wave = t >> 6, lane = t & 63;
  int quad = lane >> 4, m = lane & 15;
  int n0 = blockIdx.x * 64 + wave * 16;
  int blk = blockIdx.x * 64;
  bool valid = (n0 < N);

  // ---- phase 1: sage2 dual GEMM
  f4v acc[8];
#pragma unroll
  for (int ct = 0; ct < 8; ++ct) acc[ct] = (f4v){0.f, 0.f, 0.f, 0.f};
  if (valid) {
    const unsigned short* a1p = A1 + (size_t)(n0 + m) * 128 + quad * 8;
    const unsigned short* a2p = A2 + (size_t)(n0 + m) * 128 + quad * 8;
#pragma unroll
    for (int k0 = 0; k0 < 128; k0 += 32) {
      s8v a1 = *(const s8v*)(a1p + k0);
      s8v a2 = *(const s8v*)(a2p + k0);
#pragma unroll
      for (int ct = 0; ct < 8; ++ct) {
        s8v b1 = *(const s8v*)(Wlt + (size_t)(ct * 16 + m) * 128 + k0 + quad * 8);
        acc[ct] = __builtin_amdgcn_mfma_f32_16x16x32_bf16(a1, b1, acc[ct], 0, 0, 0);
        s8v b2 = *(const s8v*)(Wrt + (size_t)(ct * 16 + m) * 128 + k0 + quad * 8);
        acc[ct] = __builtin_amdgcn_mfma_f32_16x16x32_bf16(a2, b2, acc[ct], 0, 0, 0);
      }
    }
#pragma unroll
    for (int ct = 0; ct < 8; ++ct) {
      int col = ct * 16 + m;
      float b = bl[col];
#pragma unroll
      for (int r = 0; r < 4; ++r)
        lds[(wave * 16 + quad * 4 + r) * RS + col] = fmaxf(acc[ct][r] + b, 0.0f);
    }
  }
  __syncthreads();

  // ---- h2 fp32 coalesced store (float4) + phase-2 A-fragment read (both read LDS)
  for (int idx = t; idx < 64 * 32; idx += 256) {
    int row = idx >> 5;
    int c4 = idx & 31;
    int gr = blk + row;
    if (gr < N)
      *(f4v*)(h2out + (size_t)gr * 128 + c4 * 4) = *(const f4v*)&lds[row * RS + c4 * 4];
  }
  int arow = wave * 16 + m;
  s8v af[4];
#pragma unroll
  for (int kk = 0; kk < 4; ++kk) {
    int k0 = kk * 32 + quad * 8;
    f4v x0 = *(const f4v*)&lds[arow * RS + k0];
    f4v x1 = *(const f4v*)&lds[arow * RS + k0 + 4];
    s8v a;
#pragma unroll
    for (int i = 0; i < 4; ++i) { a[i] = (short)f2bf(x0[i]); a[4 + i] = (short)f2bf(x1[i]); }
    af[kk] = a;
  }

  // ---- phase 2: y1 = h2b @ W1 + b1
  f4v acc2[8];
#pragma unroll
  for (int ct = 0; ct < 8; ++ct) acc2[ct] = (f4v){0.f, 0.f, 0.f, 0.f};
#pragma unroll
  for (int kk = 0; kk < 4; ++kk) {
    int k0 = kk * 32;
#pragma unroll
    for (int ct = 0; ct < 8; ++ct) {
      s8v b1v = *(const s8v*)(W1t + (size_t)(ct * 16 + m) * 128 + k0 + quad * 8);
      acc2[ct] = __builtin_amdgcn_mfma_f32_16x16x32_bf16(af[kk], b1v, acc2[ct], 0, 0, 0);
    }
  }
  __syncthreads();   // all LDS reads (h2 store + frags) done; safe to overwrite
  if (valid) {
#pragma unroll
    for (int ct = 0; ct < 8; ++ct) {
      int col = ct * 16 + m;
      float b = b1[col];
#pragma unroll
      for (int r = 0; r < 4; ++r)
        lds[(wave * 16 + quad * 4 + r) * RS + col] = acc2[ct][r] + b;
    }
  }
  __syncthreads();

  // ---- y1b store + col stats (col = t&127 constant per thread)
  float s = 0.0f, ss = 0.0f;
  for (int idx = t; idx < 64 * 128; idx += 256) {
    int row = idx >> 7;
    int col = idx & 127;
    int gr = blk + row;
    if (gr < N) {
      float v = lds[row * RS + col];
      y1b[(size_t)gr * 128 + col] = f2bf(v);
      s += v; ss += v * v;
    }
  }
  red[t] = s;
  red[256 + t] = ss;
  __syncthreads();
  if (t < 128) {
    float S = red[t] + red[t + 128];
    float SS = red[256 + t] + red[256 + t + 128];
    int slot = (blockIdx.x & 7) * 128 + t;
    atomicAdd(&sum[slot], S);
    atomicAdd(&sq[slot], SS);
  }
}

// --------- BN (train) + ReLU: bf16 in -> bf16 out (C = 128, 8 stat slots), 4 elems/thr
__global__ __launch_bounds__(256) void bn_relu_kernel(const unsigned short* __restrict__ y,
    int N, const float* __restrict__ sum, const float* __restrict__ sumsq,
    const float* __restrict__ g, const float* __restrict__ be,
    unsigned short* __restrict__ yb) {
  int t4 = blockIdx.x * 256 + threadIdx.x;
  if (t4 >= N * 32) return;
  int col0 = (t4 & 31) * 4;
  float invN = 1.0f / (float)N;
  u4v in = *(const u4v*)(y + (size_t)t4 * 4);
  u4v outv;
#pragma unroll
  for (int i = 0; i < 4; ++i) {
    int col = col0 + i;
    float S = 0.0f, SS = 0.0f;
#pragma unroll
    for (int k = 0; k < 8; ++k) { S += sum[k * 128 + col]; SS += sumsq[k * 128 + col]; }
    float m = S * invN;
    float v = SS * invN - m * m;
    float val = (bf2f(in[i]) - m) * rsqrtf(v + BN_EPS) * g[col] + be[col];
    outv[i] = f2bf(fmaxf(val, 0.0f));
  }
  *(u4v*)(yb + (size_t)t4 * 4) = outv;
}

// ---------- fused BN(train)+ReLU (64 cols, 8 stat slots) + head dot: out = z2@W3+b3
__global__ __launch_bounds__(256) void bn_head_kernel(const float* __restrict__ y2,
    const float* __restrict__ sum, const float* __restrict__ sumsq,
    const float* __restrict__ g, const float* __restrict__ be,
    const float* __restrict__ W3, const float* __restrict__ b3,
    float* __restrict__ out, int N) {
  int wave = threadIdx.x >> 6;
  int lane = threadIdx.x & 63;
  int row = blockIdx.x * 4 + wave;
  if (row >= N) return;
  float S = 0.0f, SS = 0.0f;
#pragma unroll
  for (int k = 0; k < 8; ++k) { S += sum[k * 64 + lane]; SS += sumsq[k * 64 + lane]; }
  float invN = 1.0f / (float)N;
  float m = S * invN;
  float var = SS * invN - m * m;
  float val = (y2[(size_t)row * 64 + lane] - m) * rsqrtf(var + BN_EPS) * g[lane] + be[lane];
  val = fmaxf(val, 0.0f) * W3[lane];
#pragma unroll
  for (int off = 32; off > 0; off >>= 1) val += __shfl_down(val, off);
  if (lane == 0) out[row] = val + b3[0];
}

// ================================================================ launch
extern "C" void kernel_launch(void* const* d_in, const int* in_sizes, int n_in,
                              void* d_out, int out_size, void* d_ws, size_t ws_size,
                              hipStream_t stream) {
  const int F = 100, H = 128;
  const int N = in_sizes[0] / F;
  const int E = in_sizes[1] / 2;

  const float* x   = (const float*)d_in[0];
  const int* edge  = (const int*)d_in[1];
  const int* src   = edge;
  const int* dst   = edge + E;
  const float* Wl1 = (const float*)d_in[2];
  const float* bl1 = (const float*)d_in[3];
  const float* Wr1 = (const float*)d_in[4];
  const float* Wl2 = (const float*)d_in[5];
  const float* bl2 = (const float*)d_in[6];
  const float* Wr2 = (const float*)d_in[7];
  const float* W1  = (const float*)d_in[8];
  const float* b1  = (const float*)d_in[9];
  const float* g1  = (const float*)d_in[10];
  const float* be1 = (const float*)d_in[11];
  const float* W2  = (const float*)d_in[12];
  const float* b2  = (const float*)d_in[13];
  const float* g2  = (const float*)d_in[14];
  const float* be2 = (const float*)d_in[15];
  const float* W3  = (const float*)d_in[16];
  const float* b3  = (const float*)d_in[17];

  float* out0 = (float*)d_out;              // [N]
  float* h1   = out0 + N;                   // [N,128] fp32 (required output)
  float* h2   = h1 + (size_t)N * H;         // [N,128] fp32 (required output)

  const int SCAN_G = (N + 1023) / 1024;     // 49
  const int NB = (N + 127) / 128;           // 391 buckets

  // ---- workspace layout
  char* wsp = (char*)d_ws;
  int* deg       = (int*)wsp;               wsp += (size_t)N * sizeof(int);
  int* row_start = (int*)wsp;               wsp += (size_t)N * sizeof(int);
  int* eidx      = (int*)wsp;               wsp += (size_t)E * sizeof(int);
  unsigned* pairs = (unsigned*)wsp;         wsp += (size_t)E * sizeof(unsigned);
  int* gcursor   = (int*)wsp;               wsp += 512 * sizeof(int);
  int* partials  = (int*)wsp;               wsp += 256 * sizeof(int);
  int* blk_off   = (int*)wsp;               wsp += 256 * sizeof(int);
  float* sum1    = (float*)wsp;             wsp += 8 * 128 * sizeof(float);
  float* sq1     = (float*)wsp;             wsp += 8 * 128 * sizeof(float);
  float* sum2    = (float*)wsp;             wsp += 8 * 64 * sizeof(float);
  float* sq2     = (float*)wsp;             wsp += 8 * 64 * sizeof(float);
  float* bufA    = (float*)wsp;             wsp += (size_t)N * 128 * sizeof(float);
  unsigned short* bfX = (unsigned short*)wsp; wsp += (size_t)N * 128 * 2; // xb -> z1b
  unsigned short* bfM = (unsigned short*)wsp; wsp += (size_t)N * 128 * 2; // mean1b/mean2b
  unsigned short* bfH = (unsigned short*)wsp; wsp += (size_t)N * 128 * 2; // h1b
  unsigned short* Wl1t = (unsigned short*)wsp; wsp += 128 * 128 * 2;
  unsigned short* Wr1t = (unsigned short*)wsp; wsp += 128 * 128 * 2;
  unsigned short* Wl2t = (unsigned short*)wsp; wsp += 128 * 128 * 2;
  unsigned short* Wr2t = (unsigned short*)wsp; wsp += 128 * 128 * 2;
  unsigned short* W1t  = (unsigned short*)wsp; wsp += 128 * 128 * 2;
  unsigned short* W2t  = (unsigned short*)wsp; wsp += 64 * 128 * 2;

  unsigned short* y1b = (unsigned short*)bufA;                    // [N,128] bf16
  float* y2 = (float*)((char*)bufA + (size_t)N * 128 * 2);        // [N,64] fp32

  // ---- zero-init accumulated scratch (ws poisoned 0xAA each call)
  hipMemsetAsync(deg, 0, (size_t)N * sizeof(int), stream);
  hipMemsetAsync(sum1, 0, (8 * 128 + 8 * 128 + 8 * 64 + 8 * 64) * sizeof(float), stream);

  // ---- build CSR (dst -> list of src)
  deg_kernel<<<(E + 255) / 256, 256, 0, stream>>>(dst, deg, E);
  scan_partial_kernel<<<SCAN_G, 256, 0, stream>>>(deg, partials, N);
  scan_offsets_kernel<<<1, 256, 0, stream>>>(partials, blk_off, SCAN_G);
  scan_scatter_kernel<<<SCAN_G, 256, 0, stream>>>(deg, blk_off, row_start, gcursor, N);
  csr_bucket_kernel<<<(E + CHUNK - 1) / CHUNK, 256, 0, stream>>>(src, dst, gcursor, pairs, E);
  csr_fill_kernel<<<NB, 256, 0, stream>>>(pairs, row_start, eidx, N, E);

  // ---- fused bf16 prep (xcast + all weight transposes)
  int xblocks = ((size_t)N * 128 + 255) / 256;
  prep_kernel<<<xblocks + 352, 256, 0, stream>>>(x, bfX,
      Wl1, Wr1, Wl2, Wr2, W1, W2, Wl1t, Wr1t, Wl2t, Wr2t, W1t, W2t, N, xblocks);

  int gemm_grid = (N + 63) / 64;

  // ---- layer 1: gather-mean(xb) -> bfM; sage GEMM -> h1 (fp32) + h1b (bfH)
  gather_kernel<<<(N + 3) / 4, 256, 0, stream>>>(bfX, eidx, row_start, deg, bfM, N);
  mfma_gemm_kernel<128, true, true, true, true, false><<<gemm_grid, 256, 0, stream>>>(
      bfM, Wl1t, bfX, Wr1t, bl1, h1, bfH, nullptr, nullptr, N);

  // ---- layer 2: gather-mean(h1b) -> bfM; fused sage2+MLP1 -> h2, y1b, stats1
  gather_kernel<<<(N + 3) / 4, 256, 0, stream>>>(bfH, eidx, row_start, deg, bfM, N);
  sage_mlp_kernel<<<gemm_grid, 256, 0, stream>>>(
      bfM, Wl2t, bfH, Wr2t, bl2, W1t, b1, h2, y1b, sum1, sq1, N);

  // ---- BN+ReLU -> z1b (bfX)
  bn_relu_kernel<<<((size_t)N * 32 + 255) / 256, 256, 0, stream>>>(
      y1b, N, sum1, sq1, g1, be1, bfX);

  // ---- MLP layer 2: y2 = z1b @ W2 + b2 (fp32) + fused col stats
  mfma_gemm_kernel<64, false, false, true, false, true><<<gemm_grid, 256, 0, stream>>>(
      bfX, W2t, nullptr, nullptr, b2, y2, nullptr, sum2, sq2, N);

  // ---- fused BN+ReLU+head: out = relu(bn(y2)) @ W3 + b3
  bn_head_kernel<<<(N + 3) / 4, 256, 0, stream>>>(
      y2, sum2, sq2, g2, be2, W3, b3, out0, N);
}